// Round 2
// baseline (281.616 us; speedup 1.0000x reference)
//
#include <hip/hip_runtime.h>
#include <hip/hip_bf16.h>
#include <stdint.h>

#define NUM_NODES 100000
#define NUM_EDGES 50000
#define NUM_CONN  800000
#define IN_DIM    256
#define HIDDEN    128
#define EDGE_DIM  17
#define PAD       64
#define CSTRIDE   16   /* counts padded to one 64B line per edge: kills same-line atomic serialization */

typedef __bf16 bf16x8 __attribute__((ext_vector_type(8)));
typedef float  f32x4  __attribute__((ext_vector_type(4)));

// ---------------- ws layout ----------------
// P      : bf16 [NUM_NODES][HIDDEN]    25,600,000 B @ 0
// counts2: int  [NUM_EDGES*16]          3,200,000 B @ 25,600,000
// slots  : int  [NUM_EDGES][PAD]       12,800,000 B @ 28,800,000
// W1F    : bf16 frag-major [8][8][64][8]   65,536 B @ 41,600,000
// W2F    : bf16 frag-major [4][2][64][8]    8,192 B @ 41,665,536

// Zero padded counts + pack W1/W2 into MFMA B-fragment-major bf16.
__global__ void prep_kernel(const float* __restrict__ W1, const float* __restrict__ W2,
                            __bf16* __restrict__ w1f, __bf16* __restrict__ w2f,
                            int* __restrict__ counts2) {
    int i = blockIdx.x * 256 + threadIdx.x;   // grid 196*256 = 50176
    if (i < NUM_EDGES) {
        int4 z = {0, 0, 0, 0};
        int4* c4 = (int4*)(counts2 + (size_t)i * CSTRIDE);
        c4[0] = z; c4[1] = z; c4[2] = z; c4[3] = z;
    }
    if (i < 4096) {            // W1F[kc2][t][lane][ki]
        int lane = i & 63, t = (i >> 6) & 7, kc2 = i >> 9;
        int m = lane & 15, q = lane >> 4;
        int n = t * 16 + m;
        int kbase = kc2 * 32 + q * 8;
        __bf16* dst = w1f + (size_t)i * 8;
        #pragma unroll
        for (int ki = 0; ki < 8; ++ki)
            dst[ki] = (__bf16)W1[(size_t)(kbase + ki) * HIDDEN + n];
    } else if (i < 4608) {     // W2F[ks][t][lane][ki], n>=17 zero-padded
        int f = i - 4096;
        int lane = f & 63, t = (f >> 6) & 1, ks = f >> 7;
        int m = lane & 15, q = lane >> 4;
        int n = t * 16 + m;
        int kbase = ks * 32 + q * 8;
        __bf16* dst = w2f + (size_t)f * 8;
        #pragma unroll
        for (int ki = 0; ki < 8; ++ki)
            dst[ki] = (n < EDGE_DIM) ? (__bf16)W2[(size_t)(kbase + ki) * EDGE_DIM + n]
                                     : (__bf16)0.0f;
    }
}

// Fused bucket + proj.
// odd blockIdx  -> bucket role (392 blocks, 8 conns/thread, line-padded counters)
// even blockIdx -> proj role (392 blocks; each = one 64-col half of W x 512 rows)
// Proj stages its 32 KB W-half into LDS ONCE (single barrier), then loops 8
// row-tiles with software-pipelined A loads (issue t+1's loads before t's MFMAs).
// Whole 784-block grid is co-resident (~3 blocks/CU at 32 KB LDS), so bucket
// atomics overlap proj compute with no block turnover.
#define FRONT_BLOCKS 784
__global__ __launch_bounds__(256, 2) void front_kernel(const int* __restrict__ idx,
        int stride, int* __restrict__ counts2, int* __restrict__ slots,
        const float* __restrict__ nf, const __bf16* __restrict__ w1f,
        __bf16* __restrict__ pbf) {
    __shared__ __align__(16) __bf16 lds_w[16384];   // 32 KB: one 64-col half of W1F
    if (blockIdx.x & 1) {
        // ---- bucket role: 8 conns/thread, padded counters ----
        long c0 = ((long)(blockIdx.x >> 1) * 256 + threadIdx.x) * 8;
        if (c0 < NUM_CONN) {
            int nd[8], ed[8];
            if (stride == 2) {   // int64: int4 = 2 elems (lo words .x/.z)
                #pragma unroll
                for (int k = 0; k < 4; ++k) {
                    int4 vn = ((const int4*)idx)[c0 / 2 + k];
                    int4 ve = ((const int4*)(idx + 2 * NUM_CONN))[c0 / 2 + k];
                    nd[2 * k] = vn.x; nd[2 * k + 1] = vn.z;
                    ed[2 * k] = ve.x; ed[2 * k + 1] = ve.z;
                }
            } else {             // int32: int4 = 4 elems
                #pragma unroll
                for (int k = 0; k < 2; ++k) {
                    int4 vn = ((const int4*)idx)[c0 / 4 + k];
                    int4 ve = ((const int4*)(idx + NUM_CONN))[c0 / 4 + k];
                    nd[4 * k] = vn.x; nd[4 * k + 1] = vn.y;
                    nd[4 * k + 2] = vn.z; nd[4 * k + 3] = vn.w;
                    ed[4 * k] = ve.x; ed[4 * k + 1] = ve.y;
                    ed[4 * k + 2] = ve.z; ed[4 * k + 3] = ve.w;
                }
            }
            int pos[8];
            #pragma unroll
            for (int k = 0; k < 8; ++k)
                pos[k] = atomicAdd(&counts2[(size_t)ed[k] * CSTRIDE], 1);
            #pragma unroll
            for (int k = 0; k < 8; ++k)
                if (pos[k] < PAD) slots[(size_t)ed[k] * PAD + pos[k]] = nd[k];
        }
        return;
    }
    // ---- proj role ----
    const int pid = blockIdx.x >> 1;   // 0..391
    const int H = pid & 1;             // column half: cols [H*64, H*64+64)
    const int rg = pid >> 1;           // row group: rows [rg*512, rg*512+512)
    const int wave = threadIdx.x >> 6;
    const int lane = threadIdx.x & 63;
    const int m = lane & 15, q = lane >> 4;
    const int row0 = rg * 512 + wave * 16 + m;

    // stage this block's 32 KB W-half (tt-global = H*4 .. H*4+3), once
    {
        const uint4* src = (const uint4*)w1f;
        uint4* dst = (uint4*)lds_w;
        #pragma unroll
        for (int i = threadIdx.x; i < 2048; i += 256) {
            int kc2 = i >> 8, tt = (i >> 6) & 3, l = i & 63;
            dst[i] = src[(kc2 * 8 + H * 4 + tt) * 64 + l];
        }
    }
    // prefetch tile 0's A rows (in flight across the barrier drain)
    float4 a4[8];
    {
        int r = row0;
        if (r >= NUM_NODES) r = NUM_NODES - 1;
        const float* ap = nf + (size_t)r * IN_DIM + q * 8;
        #pragma unroll
        for (int kc2 = 0; kc2 < 8; ++kc2) {
            a4[2 * (kc2 & 3)]     = *(const float4*)(ap + kc2 * 32);
            a4[2 * (kc2 & 3) + 1] = *(const float4*)(ap + kc2 * 32 + 4);
            if (kc2 == 3) { /* keep two 4-batch groups like r0 to bound pressure */ }
        }
        // NOTE: a4 holds 8 float4 = full 256-float row slice for this lane's (q) k-offsets
        // layout: a4[2*kc2], a4[2*kc2+1] for kc2 0..3 then reused 4..7 below
    }
    __syncthreads();

    const bf16x8* frag = (const bf16x8*)lds_w;

    // NOTE on a4 layout: we keep all 8 float4 live (indices 2*kc2c+{0,1}, kc2c=kc2&3
    // was a staging artifact above — rewritten cleanly here):
    // a4[j] for j=0..7 covers kc2=j>>1, half=(j&1).
    // First tile's loads above used the same mapping via (kc2&3)*2 — fix by reloading
    // deterministically for kc2 4..7 was skipped; so reload full tile 0 here cleanly:
    {
        int r = row0;
        if (r >= NUM_NODES) r = NUM_NODES - 1;
        const float* ap = nf + (size_t)r * IN_DIM + q * 8;
        #pragma unroll
        for (int kc2 = 0; kc2 < 8; ++kc2) {
            a4[kc2] = *(const float4*)(ap + kc2 * 32);
        }
        // second halves fetched inside the loop below
    }

    #pragma unroll 1
    for (int t = 0; t < 8; ++t) {
        // gather second 16B of each kc2 block for current tile, convert to frags
        bf16x8 afr[8];
        {
            int r = row0 + t * 64;
            if (r >= NUM_NODES) r = NUM_NODES - 1;
            const float* ap = nf + (size_t)r * IN_DIM + q * 8;
            float4 b4[8];
            #pragma unroll
            for (int kc2 = 0; kc2 < 8; ++kc2)
                b4[kc2] = *(const float4*)(ap + kc2 * 32 + 4);
            #pragma unroll
            for (int kc2 = 0; kc2 < 8; ++kc2) {
                float4 f0 = a4[kc2], f1 = b4[kc2];
                afr[kc2][0] = (__bf16)f0.x; afr[kc2][1] = (__bf16)f0.y;
                afr[kc2][2] = (__bf16)f0.z; afr[kc2][3] = (__bf16)f0.w;
                afr[kc2][4] = (__bf16)f1.x; afr[kc2][5] = (__bf16)f1.y;
                afr[kc2][6] = (__bf16)f1.z; afr[kc2][7] = (__bf16)f1.w;
            }
        }
        // issue next tile's first-half loads now: in flight under the MFMAs
        if (t < 7) {
            int r = row0 + (t + 1) * 64;
            if (r >= NUM_NODES) r = NUM_NODES - 1;
            const float* ap = nf + (size_t)r * IN_DIM + q * 8;
            #pragma unroll
            for (int kc2 = 0; kc2 < 8; ++kc2)
                a4[kc2] = *(const float4*)(ap + kc2 * 32);
        }

        f32x4 acc[4];
        #pragma unroll
        for (int tt = 0; tt < 4; ++tt) acc[tt] = (f32x4){0.f, 0.f, 0.f, 0.f};
        #pragma unroll
        for (int kc2 = 0; kc2 < 8; ++kc2) {
            #pragma unroll
            for (int tt = 0; tt < 4; ++tt)
                acc[tt] = __builtin_amdgcn_mfma_f32_16x16x32_bf16(
                    afr[kc2], frag[(kc2 * 4 + tt) * 64 + lane], acc[tt], 0, 0, 0);
        }

        const int ob = rg * 512 + t * 64 + wave * 16 + q * 4;
        #pragma unroll
        for (int tt = 0; tt < 4; ++tt) {
            int col = H * 64 + tt * 16 + m;
            #pragma unroll
            for (int r = 0; r < 4; ++r) {
                int orow = ob + r;
                if (orow < NUM_NODES)
                    pbf[(size_t)orow * HIDDEN + col] = (__bf16)acc[tt][r];
            }
        }
    }
}

// 4 edges/wave, 16 lanes/edge gather + LN + ReLU, then the block's 16 edges
// (= one MFMA tile) go through LDS and wave 0 computes out = r@W2 + b2.
__global__ __launch_bounds__(256) void edge_kernel(const uint4* __restrict__ p4,
        const int* __restrict__ counts2, const int* __restrict__ slots,
        const float* __restrict__ b1, const float* __restrict__ ln_g,
        const float* __restrict__ ln_b, const __bf16* __restrict__ w2f,
        const float* __restrict__ b2, float* __restrict__ out) {
    __shared__ __align__(16) uint4 lds_r[256];   // 16 edges x 128 bf16 = 4 KB
    const int wave = threadIdx.x >> 6;
    const int lane = threadIdx.x & 63;
    const int g = lane & 15, ge = lane >> 4;
    const int el = wave * 4 + ge;                 // edge-local 0..15
    const int e = blockIdx.x * 16 + el;

    const int c = counts2[(size_t)e * CSTRIDE];
    const int cc = c < PAD ? c : PAD;
    const float inv = 1.0f / (float)(c > 0 ? c : 1);

    float acc[8];
    #pragma unroll
    for (int d = 0; d < 8; ++d) acc[d] = 0.f;

    for (int c0 = 0; c0 < cc; c0 += 16) {
        int slv = slots[(size_t)e * PAD + c0 + g];
        int lim = cc - c0; if (lim > 16) lim = 16;
        if (lim == 16) {
            #pragma unroll
            for (int k0 = 0; k0 < 16; k0 += 4) {
                uint4 u[4];
                #pragma unroll
                for (int k = 0; k < 4; ++k) {
                    int nd = __shfl(slv, ge * 16 + k0 + k, 64);
                    u[k] = p4[(size_t)nd * 16 + g];
                }
                #pragma unroll
                for (int k = 0; k < 4; ++k) {
                    acc[0] += __uint_as_float(u[k].x << 16);
                    acc[1] += __uint_as_float(u[k].x & 0xffff0000u);
                    acc[2] += __uint_as_float(u[k].y << 16);
                    acc[3] += __uint_as_float(u[k].y & 0xffff0000u);
                    acc[4] += __uint_as_float(u[k].z << 16);
                    acc[5] += __uint_as_float(u[k].z & 0xffff0000u);
                    acc[6] += __uint_as_float(u[k].w << 16);
                    acc[7] += __uint_as_float(u[k].w & 0xffff0000u);
                }
            }
        } else {
            for (int k0 = 0; k0 < lim; k0 += 4) {
                uint4 u[4];
                unsigned okm[4];
                #pragma unroll
                for (int k = 0; k < 4; ++k) {
                    int nd = __shfl(slv, ge * 16 + k0 + k, 64);
                    nd = ((unsigned)nd < NUM_NODES) ? nd : 0;
                    u[k] = p4[(size_t)nd * 16 + g];
                    okm[k] = (k0 + k < lim) ? 0xffffffffu : 0u;
                }
                #pragma unroll
                for (int k = 0; k < 4; ++k) {
                    uint4 v = u[k];
                    v.x &= okm[k]; v.y &= okm[k]; v.z &= okm[k]; v.w &= okm[k];
                    acc[0] += __uint_as_float(v.x << 16);
                    acc[1] += __uint_as_float(v.x & 0xffff0000u);
                    acc[2] += __uint_as_float(v.y << 16);
                    acc[3] += __uint_as_float(v.y & 0xffff0000u);
                    acc[4] += __uint_as_float(v.z << 16);
                    acc[5] += __uint_as_float(v.z & 0xffff0000u);
                    acc[6] += __uint_as_float(v.w << 16);
                    acc[7] += __uint_as_float(v.w & 0xffff0000u);
                }
            }
        }
    }

    float4 bA = ((const float4*)b1)[2 * g];
    float4 bB = ((const float4*)b1)[2 * g + 1];
    float h[8];
    h[0] = acc[0] * inv + bA.x; h[1] = acc[1] * inv + bA.y;
    h[2] = acc[2] * inv + bA.z; h[3] = acc[3] * inv + bA.w;
    h[4] = acc[4] * inv + bB.x; h[5] = acc[5] * inv + bB.y;
    h[6] = acc[6] * inv + bB.z; h[7] = acc[7] * inv + bB.w;

    float s = 0.f;
    #pragma unroll
    for (int d = 0; d < 8; ++d) s += h[d];
    #pragma unroll
    for (int off = 8; off > 0; off >>= 1) s += __shfl_xor(s, off, 64);
    float mu = s * (1.0f / 128.0f);

    float dv[8], vv = 0.f;
    #pragma unroll
    for (int d = 0; d < 8; ++d) { dv[d] = h[d] - mu; vv += dv[d] * dv[d]; }
    #pragma unroll
    for (int off = 8; off > 0; off >>= 1) vv += __shfl_xor(vv, off, 64);
    float rs = rsqrtf(vv * (1.0f / 128.0f) + 1e-5f);

    float4 gA = ((const float4*)ln_g)[2 * g];
    float4 gB = ((const float4*)ln_g)[2 * g + 1];
    float4 eA = ((const float4*)ln_b)[2 * g];
    float4 eB = ((const float4*)ln_b)[2 * g + 1];
    float gg[8] = {gA.x, gA.y, gA.z, gA.w, gB.x, gB.y, gB.z, gB.w};
    float ee[8] = {eA.x, eA.y, eA.z, eA.w, eB.x, eB.y, eB.z, eB.w};
    union { __bf16 b[8]; uint4 u; } pk;
    #pragma unroll
    for (int d = 0; d < 8; ++d) {
        float r = dv[d] * rs * gg[d] + ee[d];
        pk.b[d] = (__bf16)(r > 0.f ? r : 0.f);
    }
    lds_r[el * 16 + g] = pk.u;
    __syncthreads();

    if (wave == 0) {   // out tile: [16 edges x 128] @ [128 x 32pad]
        const int m = lane & 15, q = lane >> 4;
        const __bf16* lr = (const __bf16*)lds_r;
        const bf16x8* fw = (const bf16x8*)w2f;
        f32x4 a0 = (f32x4){0.f, 0.f, 0.f, 0.f};
        f32x4 a1 = (f32x4){0.f, 0.f, 0.f, 0.f};
        #pragma unroll
        for (int ks = 0; ks < 4; ++ks) {
            bf16x8 a = *(const bf16x8*)(lr + m * 128 + ks * 32 + q * 8);
            a0 = __builtin_amdgcn_mfma_f32_16x16x32_bf16(a, fw[(ks * 2 + 0) * 64 + lane], a0, 0, 0, 0);
            a1 = __builtin_amdgcn_mfma_f32_16x16x32_bf16(a, fw[(ks * 2 + 1) * 64 + lane], a1, 0, 0, 0);
        }
        int rowb = blockIdx.x * 16 + q * 4;
        float bm = b2[m];
        float b16 = b2[16];
        #pragma unroll
        for (int r = 0; r < 4; ++r) {
            out[(size_t)(rowb + r) * EDGE_DIM + m] = a0[r] + bm;
            if (m == 0) out[(size_t)(rowb + r) * EDGE_DIM + 16] = a1[r] + b16;
        }
    }
}

extern "C" void kernel_launch(void* const* d_in, const int* in_sizes, int n_in,
                              void* d_out, int out_size, void* d_ws, size_t ws_size,
                              hipStream_t stream) {
    const float* nf  = (const float*)d_in[0];
    const int*   idx = (const int*)d_in[1];
    const float* W1  = (const float*)d_in[2];
    const float* b1  = (const float*)d_in[3];
    const float* g   = (const float*)d_in[4];
    const float* be  = (const float*)d_in[5];
    const float* W2  = (const float*)d_in[6];
    const float* b2  = (const float*)d_in[7];
    float* out = (float*)d_out;

    char* ws = (char*)d_ws;
    __bf16* P       = (__bf16*)ws;
    int*    counts2 = (int*)(ws + 25600000);
    int*    slots   = (int*)(ws + 28800000);
    __bf16* W1F     = (__bf16*)(ws + 41600000);
    __bf16* W2F     = (__bf16*)(ws + 41665536);

    int stride = (in_sizes[1] == 2 * NUM_CONN) ? 1 : 2;

    prep_kernel<<<196, 256, 0, stream>>>(W1, W2, W1F, W2F, counts2);
    front_kernel<<<FRONT_BLOCKS, 256, 0, stream>>>(idx, stride, counts2, slots, nf, W1F, P);
    edge_kernel<<<NUM_EDGES / 16, 256, 0, stream>>>((const uint4*)P, counts2, slots,
                                                    b1, g, be, W2F, b2, out);
}

// Round 3
// 255.118 us; speedup vs baseline: 1.1039x; 1.1039x over previous
//
#include <hip/hip_runtime.h>
#include <hip/hip_bf16.h>
#include <stdint.h>

#define NUM_NODES 100000
#define NUM_EDGES 50000
#define NUM_CONN  800000
#define IN_DIM    256
#define HIDDEN    128
#define EDGE_DIM  17
#define PAD       64
#define CSTRIDE   16   /* counts padded to one 64B line per edge: kills same-line atomic serialization */

typedef __bf16 bf16x8 __attribute__((ext_vector_type(8)));
typedef float  f32x4  __attribute__((ext_vector_type(4)));

// ---------------- ws layout ----------------
// P      : bf16 [NUM_NODES][HIDDEN]    25,600,000 B @ 0
// counts2: int  [NUM_EDGES*16]          3,200,000 B @ 25,600,000
// slots  : int  [NUM_EDGES][PAD]       12,800,000 B @ 28,800,000
// W1F    : bf16 frag-major [8][8][64][8]   65,536 B @ 41,600,000
// W2F    : bf16 frag-major [4][2][64][8]    8,192 B @ 41,665,536

// Zero padded counts + pack W1/W2 into MFMA B-fragment-major bf16.
__global__ void prep_kernel(const float* __restrict__ W1, const float* __restrict__ W2,
                            __bf16* __restrict__ w1f, __bf16* __restrict__ w2f,
                            int* __restrict__ counts2) {
    int i = blockIdx.x * 256 + threadIdx.x;   // grid 196*256 = 50176
    if (i < NUM_EDGES) {
        int4 z = {0, 0, 0, 0};
        int4* c4 = (int4*)(counts2 + (size_t)i * CSTRIDE);
        c4[0] = z; c4[1] = z; c4[2] = z; c4[3] = z;
    }
    if (i < 4096) {            // W1F[kc2][t][lane][ki]
        int lane = i & 63, t = (i >> 6) & 7, kc2 = i >> 9;
        int m = lane & 15, q = lane >> 4;
        int n = t * 16 + m;
        int kbase = kc2 * 32 + q * 8;
        __bf16* dst = w1f + (size_t)i * 8;
        #pragma unroll
        for (int ki = 0; ki < 8; ++ki)
            dst[ki] = (__bf16)W1[(size_t)(kbase + ki) * HIDDEN + n];
    } else if (i < 4608) {     // W2F[ks][t][lane][ki], n>=17 zero-padded
        int f = i - 4096;
        int lane = f & 63, t = (f >> 6) & 1, ks = f >> 7;
        int m = lane & 15, q = lane >> 4;
        int n = t * 16 + m;
        int kbase = ks * 32 + q * 8;
        __bf16* dst = w2f + (size_t)f * 8;
        #pragma unroll
        for (int ki = 0; ki < 8; ++ki)
            dst[ki] = (n < EDGE_DIM) ? (__bf16)W2[(size_t)(kbase + ki) * EDGE_DIM + n]
                                     : (__bf16)0.0f;
    }
}

// Fused bucket + proj (round-0 structure).
// blockIdx % 3 == 1 -> bucket role (782 blocks, 4 conns/thread, line-padded counters)
// else              -> proj role (1564 blocks; 64 rows x 128 cols, two-phase 32KB LDS)
// Round-2 change: phase-1 W half is prefetched into REGISTERS right after the
// first barrier (drains under phase-0 MFMAs+stores); the mid-kernel stage is
// then a pure LDS write instead of an exposed global->LDS round trip.
#define FRONT_BLOCKS 2346
__global__ __launch_bounds__(256, 4) void front_kernel(const int* __restrict__ idx,
        int stride, int* __restrict__ counts2, int* __restrict__ slots,
        const float* __restrict__ nf, const __bf16* __restrict__ w1f,
        __bf16* __restrict__ pbf) {
    __shared__ __align__(16) __bf16 lds_w[16384];   // 32 KB: 4 n-tiles per phase
    const int nb = blockIdx.x / 3, r3 = blockIdx.x % 3;
    if (r3 == 1) {
        // ---- bucket role: 4 conns/thread, padded counters ----
        long c0 = ((long)nb * 256 + threadIdx.x) * 4;
        if (c0 < NUM_CONN) {
            int nd[4], ed[4];
            if (stride == 2) {   // int64: int4 = 2 elems (lo words .x/.z)
                #pragma unroll
                for (int k = 0; k < 2; ++k) {
                    int4 vn = ((const int4*)idx)[c0 / 2 + k];
                    int4 ve = ((const int4*)(idx + 2 * NUM_CONN))[c0 / 2 + k];
                    nd[2 * k] = vn.x; nd[2 * k + 1] = vn.z;
                    ed[2 * k] = ve.x; ed[2 * k + 1] = ve.z;
                }
            } else {
                #pragma unroll
                for (int k = 0; k < 4; ++k) {
                    nd[k] = idx[c0 + k];
                    ed[k] = idx[NUM_CONN + c0 + k];
                }
            }
            int pos[4];
            #pragma unroll
            for (int k = 0; k < 4; ++k)
                pos[k] = atomicAdd(&counts2[(size_t)ed[k] * CSTRIDE], 1);
            #pragma unroll
            for (int k = 0; k < 4; ++k)
                if (pos[k] < PAD) slots[(size_t)ed[k] * PAD + pos[k]] = nd[k];
        }
        return;
    }
    // ---- proj role ----
    const int p = 2 * nb + (r3 == 2 ? 1 : 0);   // 0..1563
    const int wave = threadIdx.x >> 6;
    const int lane = threadIdx.x & 63;
    const int m = lane & 15, q = lane >> 4;
    int row = p * 64 + wave * 16 + m;
    if (row >= NUM_NODES) row = NUM_NODES - 1;          // clamp; stores guarded
    const float* ap = nf + (size_t)row * IN_DIM + q * 8;

    const uint4* src = (const uint4*)w1f;
    uint4* dst = (uint4*)lds_w;

    // A-tile: two 8-float4 batches (bounds VGPR pressure), convert to bf16 frags.
    bf16x8 afr[8];
    {
        float4 a4[8];
        #pragma unroll
        for (int kc2 = 0; kc2 < 4; ++kc2) {
            a4[2 * kc2]     = *(const float4*)(ap + kc2 * 32);
            a4[2 * kc2 + 1] = *(const float4*)(ap + kc2 * 32 + 4);
        }
        // stage phase-0 B half while A batch 0 is in flight
        #pragma unroll
        for (int i = threadIdx.x; i < 2048; i += 256) {
            int kc2 = i >> 8, tt = (i >> 6) & 3, l = i & 63;
            dst[i] = src[(kc2 * 8 + tt) * 64 + l];
        }
        #pragma unroll
        for (int kc2 = 0; kc2 < 4; ++kc2) {
            float4 f0 = a4[2 * kc2], f1 = a4[2 * kc2 + 1];
            afr[kc2][0] = (__bf16)f0.x; afr[kc2][1] = (__bf16)f0.y;
            afr[kc2][2] = (__bf16)f0.z; afr[kc2][3] = (__bf16)f0.w;
            afr[kc2][4] = (__bf16)f1.x; afr[kc2][5] = (__bf16)f1.y;
            afr[kc2][6] = (__bf16)f1.z; afr[kc2][7] = (__bf16)f1.w;
        }
        #pragma unroll
        for (int kc2 = 4; kc2 < 8; ++kc2) {
            a4[2 * (kc2 - 4)]     = *(const float4*)(ap + kc2 * 32);
            a4[2 * (kc2 - 4) + 1] = *(const float4*)(ap + kc2 * 32 + 4);
        }
        #pragma unroll
        for (int kc2 = 4; kc2 < 8; ++kc2) {
            float4 f0 = a4[2 * (kc2 - 4)], f1 = a4[2 * (kc2 - 4) + 1];
            afr[kc2][0] = (__bf16)f0.x; afr[kc2][1] = (__bf16)f0.y;
            afr[kc2][2] = (__bf16)f0.z; afr[kc2][3] = (__bf16)f0.w;
            afr[kc2][4] = (__bf16)f1.x; afr[kc2][5] = (__bf16)f1.y;
            afr[kc2][6] = (__bf16)f1.z; afr[kc2][7] = (__bf16)f1.w;
        }
    }
    __syncthreads();

    // T14 async-split: issue phase-1 W loads NOW; they complete under the
    // phase-0 MFMAs + stores. The mid-kernel stage becomes a pure ds_write.
    uint4 wreg[8];
    #pragma unroll
    for (int j = 0; j < 8; ++j) {
        int ii = j * 256 + threadIdx.x;
        int kc2 = ii >> 8, tt = (ii >> 6) & 3, l = ii & 63;
        wreg[j] = src[(kc2 * 8 + 4 + tt) * 64 + l];
    }

    const bf16x8* frag = (const bf16x8*)lds_w;
    #pragma unroll
    for (int ph = 0; ph < 2; ++ph) {
        f32x4 acc[4];
        #pragma unroll
        for (int tt = 0; tt < 4; ++tt) acc[tt] = (f32x4){0.f, 0.f, 0.f, 0.f};
        #pragma unroll
        for (int kc2 = 0; kc2 < 8; ++kc2) {
            #pragma unroll
            for (int tt = 0; tt < 4; ++tt)
                acc[tt] = __builtin_amdgcn_mfma_f32_16x16x32_bf16(
                    afr[kc2], frag[(kc2 * 4 + tt) * 64 + lane], acc[tt], 0, 0, 0);
        }
        int ob = p * 64 + wave * 16 + q * 4;
        #pragma unroll
        for (int tt = 0; tt < 4; ++tt) {
            int col = (ph * 4 + tt) * 16 + m;
            #pragma unroll
            for (int r = 0; r < 4; ++r) {
                int orow = ob + r;
                if (orow < NUM_NODES)
                    pbf[(size_t)orow * HIDDEN + col] = (__bf16)acc[tt][r];
            }
        }
        if (ph == 0) {
            __syncthreads();   // phase-0 LDS reads complete before overwrite
            #pragma unroll
            for (int j = 0; j < 8; ++j)
                dst[j * 256 + threadIdx.x] = wreg[j];
            __syncthreads();
        }
    }
}

// 4 edges/wave, 16 lanes/edge gather + LN + ReLU, then the block's 16 edges
// (= one MFMA tile) go through LDS and wave 0 computes out = r@W2 + b2.
__global__ __launch_bounds__(256) void edge_kernel(const uint4* __restrict__ p4,
        const int* __restrict__ counts2, const int* __restrict__ slots,
        const float* __restrict__ b1, const float* __restrict__ ln_g,
        const float* __restrict__ ln_b, const __bf16* __restrict__ w2f,
        const float* __restrict__ b2, float* __restrict__ out) {
    __shared__ __align__(16) uint4 lds_r[256];   // 16 edges x 128 bf16 = 4 KB
    const int wave = threadIdx.x >> 6;
    const int lane = threadIdx.x & 63;
    const int g = lane & 15, ge = lane >> 4;
    const int el = wave * 4 + ge;                 // edge-local 0..15
    const int e = blockIdx.x * 16 + el;

    const int c = counts2[(size_t)e * CSTRIDE];
    const int cc = c < PAD ? c : PAD;
    const float inv = 1.0f / (float)(c > 0 ? c : 1);

    float acc[8];
    #pragma unroll
    for (int d = 0; d < 8; ++d) acc[d] = 0.f;

    for (int c0 = 0; c0 < cc; c0 += 16) {
        int slv = slots[(size_t)e * PAD + c0 + g];
        int lim = cc - c0; if (lim > 16) lim = 16;
        if (lim == 16) {
            #pragma unroll
            for (int k0 = 0; k0 < 16; k0 += 4) {
                uint4 u[4];
                #pragma unroll
                for (int k = 0; k < 4; ++k) {
                    int nd = __shfl(slv, ge * 16 + k0 + k, 64);
                    u[k] = p4[(size_t)nd * 16 + g];
                }
                #pragma unroll
                for (int k = 0; k < 4; ++k) {
                    acc[0] += __uint_as_float(u[k].x << 16);
                    acc[1] += __uint_as_float(u[k].x & 0xffff0000u);
                    acc[2] += __uint_as_float(u[k].y << 16);
                    acc[3] += __uint_as_float(u[k].y & 0xffff0000u);
                    acc[4] += __uint_as_float(u[k].z << 16);
                    acc[5] += __uint_as_float(u[k].z & 0xffff0000u);
                    acc[6] += __uint_as_float(u[k].w << 16);
                    acc[7] += __uint_as_float(u[k].w & 0xffff0000u);
                }
            }
        } else {
            for (int k0 = 0; k0 < lim; k0 += 4) {
                uint4 u[4];
                unsigned okm[4];
                #pragma unroll
                for (int k = 0; k < 4; ++k) {
                    int nd = __shfl(slv, ge * 16 + k0 + k, 64);
                    nd = ((unsigned)nd < NUM_NODES) ? nd : 0;
                    u[k] = p4[(size_t)nd * 16 + g];
                    okm[k] = (k0 + k < lim) ? 0xffffffffu : 0u;
                }
                #pragma unroll
                for (int k = 0; k < 4; ++k) {
                    uint4 v = u[k];
                    v.x &= okm[k]; v.y &= okm[k]; v.z &= okm[k]; v.w &= okm[k];
                    acc[0] += __uint_as_float(v.x << 16);
                    acc[1] += __uint_as_float(v.x & 0xffff0000u);
                    acc[2] += __uint_as_float(v.y << 16);
                    acc[3] += __uint_as_float(v.y & 0xffff0000u);
                    acc[4] += __uint_as_float(v.z << 16);
                    acc[5] += __uint_as_float(v.z & 0xffff0000u);
                    acc[6] += __uint_as_float(v.w << 16);
                    acc[7] += __uint_as_float(v.w & 0xffff0000u);
                }
            }
        }
    }

    float4 bA = ((const float4*)b1)[2 * g];
    float4 bB = ((const float4*)b1)[2 * g + 1];
    float h[8];
    h[0] = acc[0] * inv + bA.x; h[1] = acc[1] * inv + bA.y;
    h[2] = acc[2] * inv + bA.z; h[3] = acc[3] * inv + bA.w;
    h[4] = acc[4] * inv + bB.x; h[5] = acc[5] * inv + bB.y;
    h[6] = acc[6] * inv + bB.z; h[7] = acc[7] * inv + bB.w;

    float s = 0.f;
    #pragma unroll
    for (int d = 0; d < 8; ++d) s += h[d];
    #pragma unroll
    for (int off = 8; off > 0; off >>= 1) s += __shfl_xor(s, off, 64);
    float mu = s * (1.0f / 128.0f);

    float dv[8], vv = 0.f;
    #pragma unroll
    for (int d = 0; d < 8; ++d) { dv[d] = h[d] - mu; vv += dv[d] * dv[d]; }
    #pragma unroll
    for (int off = 8; off > 0; off >>= 1) vv += __shfl_xor(vv, off, 64);
    float rs = rsqrtf(vv * (1.0f / 128.0f) + 1e-5f);

    float4 gA = ((const float4*)ln_g)[2 * g];
    float4 gB = ((const float4*)ln_g)[2 * g + 1];
    float4 eA = ((const float4*)ln_b)[2 * g];
    float4 eB = ((const float4*)ln_b)[2 * g + 1];
    float gg[8] = {gA.x, gA.y, gA.z, gA.w, gB.x, gB.y, gB.z, gB.w};
    float ee[8] = {eA.x, eA.y, eA.z, eA.w, eB.x, eB.y, eB.z, eB.w};
    union { __bf16 b[8]; uint4 u; } pk;
    #pragma unroll
    for (int d = 0; d < 8; ++d) {
        float r = dv[d] * rs * gg[d] + ee[d];
        pk.b[d] = (__bf16)(r > 0.f ? r : 0.f);
    }
    lds_r[el * 16 + g] = pk.u;
    __syncthreads();

    if (wave == 0) {   // out tile: [16 edges x 128] @ [128 x 32pad]
        const int m = lane & 15, q = lane >> 4;
        const __bf16* lr = (const __bf16*)lds_r;
        const bf16x8* fw = (const bf16x8*)w2f;
        f32x4 a0 = (f32x4){0.f, 0.f, 0.f, 0.f};
        f32x4 a1 = (f32x4){0.f, 0.f, 0.f, 0.f};
        #pragma unroll
        for (int ks = 0; ks < 4; ++ks) {
            bf16x8 a = *(const bf16x8*)(lr + m * 128 + ks * 32 + q * 8);
            a0 = __builtin_amdgcn_mfma_f32_16x16x32_bf16(a, fw[(ks * 2 + 0) * 64 + lane], a0, 0, 0, 0);
            a1 = __builtin_amdgcn_mfma_f32_16x16x32_bf16(a, fw[(ks * 2 + 1) * 64 + lane], a1, 0, 0, 0);
        }
        int rowb = blockIdx.x * 16 + q * 4;
        float bm = b2[m];
        float b16 = b2[16];
        #pragma unroll
        for (int r = 0; r < 4; ++r) {
            out[(size_t)(rowb + r) * EDGE_DIM + m] = a0[r] + bm;
            if (m == 0) out[(size_t)(rowb + r) * EDGE_DIM + 16] = a1[r] + b16;
        }
    }
}

extern "C" void kernel_launch(void* const* d_in, const int* in_sizes, int n_in,
                              void* d_out, int out_size, void* d_ws, size_t ws_size,
                              hipStream_t stream) {
    const float* nf  = (const float*)d_in[0];
    const int*   idx = (const int*)d_in[1];
    const float* W1  = (const float*)d_in[2];
    const float* b1  = (const float*)d_in[3];
    const float* g   = (const float*)d_in[4];
    const float* be  = (const float*)d_in[5];
    const float* W2  = (const float*)d_in[6];
    const float* b2  = (const float*)d_in[7];
    float* out = (float*)d_out;

    char* ws = (char*)d_ws;
    __bf16* P       = (__bf16*)ws;
    int*    counts2 = (int*)(ws + 25600000);
    int*    slots   = (int*)(ws + 28800000);
    __bf16* W1F     = (__bf16*)(ws + 41600000);
    __bf16* W2F     = (__bf16*)(ws + 41665536);

    int stride = (in_sizes[1] == 2 * NUM_CONN) ? 1 : 2;

    prep_kernel<<<196, 256, 0, stream>>>(W1, W2, W1F, W2F, counts2);
    front_kernel<<<FRONT_BLOCKS, 256, 0, stream>>>(idx, stride, counts2, slots, nf, W1F, P);
    edge_kernel<<<NUM_EDGES / 16, 256, 0, stream>>>((const uint4*)P, counts2, slots,
                                                    b1, g, be, W2F, b2, out);
}

// Round 4
// 235.434 us; speedup vs baseline: 1.1962x; 1.0836x over previous
//
#include <hip/hip_runtime.h>
#include <hip/hip_bf16.h>
#include <stdint.h>

#define NUM_NODES 100000
#define NUM_EDGES 50000
#define NUM_CONN  800000
#define IN_DIM    256
#define HIDDEN    128
#define EDGE_DIM  17
#define PAD       64
#define CSTRIDE   16   /* counts padded to one 64B line per edge: kills same-line atomic serialization */

typedef __bf16 bf16x8 __attribute__((ext_vector_type(8)));
typedef float  f32x4  __attribute__((ext_vector_type(4)));

// ---------------- ws layout ----------------
// P      : bf16 [NUM_NODES][HIDDEN]    25,600,000 B @ 0
// counts2: int  [NUM_EDGES*16]          3,200,000 B @ 25,600,000
// slots  : int  [NUM_EDGES][PAD]       12,800,000 B @ 28,800,000
// W1F    : bf16 frag-major [8][8][64][8]   65,536 B @ 41,600,000
// W2F    : bf16 frag-major [4][2][64][8]    8,192 B @ 41,665,536

// Zero padded counts + pack W1/W2 into MFMA B-fragment-major bf16.
__global__ void prep_kernel(const float* __restrict__ W1, const float* __restrict__ W2,
                            __bf16* __restrict__ w1f, __bf16* __restrict__ w2f,
                            int* __restrict__ counts2) {
    int i = blockIdx.x * 256 + threadIdx.x;   // grid 196*256 = 50176
    if (i < NUM_EDGES) {
        int4 z = {0, 0, 0, 0};
        int4* c4 = (int4*)(counts2 + (size_t)i * CSTRIDE);
        c4[0] = z; c4[1] = z; c4[2] = z; c4[3] = z;
    }
    if (i < 4096) {            // W1F[kc2][t][lane][ki]
        int lane = i & 63, t = (i >> 6) & 7, kc2 = i >> 9;
        int m = lane & 15, q = lane >> 4;
        int n = t * 16 + m;
        int kbase = kc2 * 32 + q * 8;
        __bf16* dst = w1f + (size_t)i * 8;
        #pragma unroll
        for (int ki = 0; ki < 8; ++ki)
            dst[ki] = (__bf16)W1[(size_t)(kbase + ki) * HIDDEN + n];
    } else if (i < 4608) {     // W2F[ks][t][lane][ki], n>=17 zero-padded
        int f = i - 4096;
        int lane = f & 63, t = (f >> 6) & 1, ks = f >> 7;
        int m = lane & 15, q = lane >> 4;
        int n = t * 16 + m;
        int kbase = ks * 32 + q * 8;
        __bf16* dst = w2f + (size_t)f * 8;
        #pragma unroll
        for (int ki = 0; ki < 8; ++ki)
            dst[ki] = (n < EDGE_DIM) ? (__bf16)W2[(size_t)(kbase + ki) * EDGE_DIM + n]
                                     : (__bf16)0.0f;
    }
}

// Fused bucket + proj (round-0 structure, restored verbatim — measured 73 us).
// blockIdx % 3 == 1 -> bucket role (782 blocks, 4 conns/thread, line-padded counters)
// else              -> proj role (1564 blocks; 64 rows x 128 cols, two-phase 32KB LDS)
#define FRONT_BLOCKS 2346
__global__ __launch_bounds__(256, 4) void front_kernel(const int* __restrict__ idx,
        int stride, int* __restrict__ counts2, int* __restrict__ slots,
        const float* __restrict__ nf, const __bf16* __restrict__ w1f,
        __bf16* __restrict__ pbf) {
    __shared__ __align__(16) __bf16 lds_w[16384];   // 32 KB: 4 n-tiles per phase
    const int nb = blockIdx.x / 3, r3 = blockIdx.x % 3;
    if (r3 == 1) {
        // ---- bucket role: 4 conns/thread, padded counters ----
        long c0 = ((long)nb * 256 + threadIdx.x) * 4;
        if (c0 < NUM_CONN) {
            int nd[4], ed[4];
            if (stride == 2) {   // int64: int4 = 2 elems (lo words .x/.z)
                #pragma unroll
                for (int k = 0; k < 2; ++k) {
                    int4 vn = ((const int4*)idx)[c0 / 2 + k];
                    int4 ve = ((const int4*)(idx + 2 * NUM_CONN))[c0 / 2 + k];
                    nd[2 * k] = vn.x; nd[2 * k + 1] = vn.z;
                    ed[2 * k] = ve.x; ed[2 * k + 1] = ve.z;
                }
            } else {
                #pragma unroll
                for (int k = 0; k < 4; ++k) {
                    nd[k] = idx[c0 + k];
                    ed[k] = idx[NUM_CONN + c0 + k];
                }
            }
            int pos[4];
            #pragma unroll
            for (int k = 0; k < 4; ++k)
                pos[k] = atomicAdd(&counts2[(size_t)ed[k] * CSTRIDE], 1);
            #pragma unroll
            for (int k = 0; k < 4; ++k)
                if (pos[k] < PAD) slots[(size_t)ed[k] * PAD + pos[k]] = nd[k];
        }
        return;
    }
    // ---- proj role ----
    const int p = 2 * nb + (r3 == 2 ? 1 : 0);   // 0..1563
    const int wave = threadIdx.x >> 6;
    const int lane = threadIdx.x & 63;
    const int m = lane & 15, q = lane >> 4;
    int row = p * 64 + wave * 16 + m;
    if (row >= NUM_NODES) row = NUM_NODES - 1;          // clamp; stores guarded
    const float* ap = nf + (size_t)row * IN_DIM + q * 8;

    const uint4* src = (const uint4*)w1f;
    uint4* dst = (uint4*)lds_w;

    // A-tile: two 8-float4 batches (bounds VGPR pressure), convert to bf16 frags.
    bf16x8 afr[8];
    {
        float4 a4[8];
        #pragma unroll
        for (int kc2 = 0; kc2 < 4; ++kc2) {
            a4[2 * kc2]     = *(const float4*)(ap + kc2 * 32);
            a4[2 * kc2 + 1] = *(const float4*)(ap + kc2 * 32 + 4);
        }
        // stage phase-0 B half while A batch 0 is in flight
        #pragma unroll
        for (int i = threadIdx.x; i < 2048; i += 256) {
            int kc2 = i >> 8, tt = (i >> 6) & 3, l = i & 63;
            dst[i] = src[(kc2 * 8 + tt) * 64 + l];
        }
        #pragma unroll
        for (int kc2 = 0; kc2 < 4; ++kc2) {
            float4 f0 = a4[2 * kc2], f1 = a4[2 * kc2 + 1];
            afr[kc2][0] = (__bf16)f0.x; afr[kc2][1] = (__bf16)f0.y;
            afr[kc2][2] = (__bf16)f0.z; afr[kc2][3] = (__bf16)f0.w;
            afr[kc2][4] = (__bf16)f1.x; afr[kc2][5] = (__bf16)f1.y;
            afr[kc2][6] = (__bf16)f1.z; afr[kc2][7] = (__bf16)f1.w;
        }
        #pragma unroll
        for (int kc2 = 4; kc2 < 8; ++kc2) {
            a4[2 * (kc2 - 4)]     = *(const float4*)(ap + kc2 * 32);
            a4[2 * (kc2 - 4) + 1] = *(const float4*)(ap + kc2 * 32 + 4);
        }
        #pragma unroll
        for (int kc2 = 4; kc2 < 8; ++kc2) {
            float4 f0 = a4[2 * (kc2 - 4)], f1 = a4[2 * (kc2 - 4) + 1];
            afr[kc2][0] = (__bf16)f0.x; afr[kc2][1] = (__bf16)f0.y;
            afr[kc2][2] = (__bf16)f0.z; afr[kc2][3] = (__bf16)f0.w;
            afr[kc2][4] = (__bf16)f1.x; afr[kc2][5] = (__bf16)f1.y;
            afr[kc2][6] = (__bf16)f1.z; afr[kc2][7] = (__bf16)f1.w;
        }
    }
    __syncthreads();

    const bf16x8* frag = (const bf16x8*)lds_w;
    #pragma unroll
    for (int ph = 0; ph < 2; ++ph) {
        f32x4 acc[4];
        #pragma unroll
        for (int tt = 0; tt < 4; ++tt) acc[tt] = (f32x4){0.f, 0.f, 0.f, 0.f};
        #pragma unroll
        for (int kc2 = 0; kc2 < 8; ++kc2) {
            #pragma unroll
            for (int tt = 0; tt < 4; ++tt)
                acc[tt] = __builtin_amdgcn_mfma_f32_16x16x32_bf16(
                    afr[kc2], frag[(kc2 * 4 + tt) * 64 + lane], acc[tt], 0, 0, 0);
        }
        int ob = p * 64 + wave * 16 + q * 4;
        #pragma unroll
        for (int tt = 0; tt < 4; ++tt) {
            int col = (ph * 4 + tt) * 16 + m;
            #pragma unroll
            for (int r = 0; r < 4; ++r) {
                int orow = ob + r;
                if (orow < NUM_NODES)
                    pbf[(size_t)orow * HIDDEN + col] = (__bf16)acc[tt][r];
            }
        }
        if (ph == 0) {
            __syncthreads();   // phase-0 LDS reads complete before overwrite
            #pragma unroll
            for (int i = threadIdx.x; i < 2048; i += 256) {
                int kc2 = i >> 8, tt = (i >> 6) & 3, l = i & 63;
                dst[i] = src[(kc2 * 8 + 4 + tt) * 64 + l];
            }
            __syncthreads();
        }
    }
}

// 4 edges/wave, 16 lanes/edge gather + LN + ReLU, then the block's 16 edges
// (= one MFMA tile) go through LDS and wave 0 computes out = r@W2 + b2.
// Round-4 change: full-tile gather path issues 8 outstanding uint4 loads
// (was 4) — doubles memory-level parallelism against L2 latency.
__global__ __launch_bounds__(256) void edge_kernel(const uint4* __restrict__ p4,
        const int* __restrict__ counts2, const int* __restrict__ slots,
        const float* __restrict__ b1, const float* __restrict__ ln_g,
        const float* __restrict__ ln_b, const __bf16* __restrict__ w2f,
        const float* __restrict__ b2, float* __restrict__ out) {
    __shared__ __align__(16) uint4 lds_r[256];   // 16 edges x 128 bf16 = 4 KB
    const int wave = threadIdx.x >> 6;
    const int lane = threadIdx.x & 63;
    const int g = lane & 15, ge = lane >> 4;
    const int el = wave * 4 + ge;                 // edge-local 0..15
    const int e = blockIdx.x * 16 + el;

    const int c = counts2[(size_t)e * CSTRIDE];
    const int cc = c < PAD ? c : PAD;
    const float inv = 1.0f / (float)(c > 0 ? c : 1);

    float acc[8];
    #pragma unroll
    for (int d = 0; d < 8; ++d) acc[d] = 0.f;

    for (int c0 = 0; c0 < cc; c0 += 16) {
        int slv = slots[(size_t)e * PAD + c0 + g];
        int lim = cc - c0; if (lim > 16) lim = 16;
        if (lim == 16) {
            #pragma unroll
            for (int k0 = 0; k0 < 16; k0 += 8) {
                uint4 u[8];
                #pragma unroll
                for (int k = 0; k < 8; ++k) {
                    int nd = __shfl(slv, ge * 16 + k0 + k, 64);
                    u[k] = p4[(size_t)nd * 16 + g];
                }
                #pragma unroll
                for (int k = 0; k < 8; ++k) {
                    acc[0] += __uint_as_float(u[k].x << 16);
                    acc[1] += __uint_as_float(u[k].x & 0xffff0000u);
                    acc[2] += __uint_as_float(u[k].y << 16);
                    acc[3] += __uint_as_float(u[k].y & 0xffff0000u);
                    acc[4] += __uint_as_float(u[k].z << 16);
                    acc[5] += __uint_as_float(u[k].z & 0xffff0000u);
                    acc[6] += __uint_as_float(u[k].w << 16);
                    acc[7] += __uint_as_float(u[k].w & 0xffff0000u);
                }
            }
        } else {
            for (int k0 = 0; k0 < lim; k0 += 4) {
                uint4 u[4];
                unsigned okm[4];
                #pragma unroll
                for (int k = 0; k < 4; ++k) {
                    int nd = __shfl(slv, ge * 16 + k0 + k, 64);
                    nd = ((unsigned)nd < NUM_NODES) ? nd : 0;
                    u[k] = p4[(size_t)nd * 16 + g];
                    okm[k] = (k0 + k < lim) ? 0xffffffffu : 0u;
                }
                #pragma unroll
                for (int k = 0; k < 4; ++k) {
                    uint4 v = u[k];
                    v.x &= okm[k]; v.y &= okm[k]; v.z &= okm[k]; v.w &= okm[k];
                    acc[0] += __uint_as_float(v.x << 16);
                    acc[1] += __uint_as_float(v.x & 0xffff0000u);
                    acc[2] += __uint_as_float(v.y << 16);
                    acc[3] += __uint_as_float(v.y & 0xffff0000u);
                    acc[4] += __uint_as_float(v.z << 16);
                    acc[5] += __uint_as_float(v.z & 0xffff0000u);
                    acc[6] += __uint_as_float(v.w << 16);
                    acc[7] += __uint_as_float(v.w & 0xffff0000u);
                }
            }
        }
    }

    float4 bA = ((const float4*)b1)[2 * g];
    float4 bB = ((const float4*)b1)[2 * g + 1];
    float h[8];
    h[0] = acc[0] * inv + bA.x; h[1] = acc[1] * inv + bA.y;
    h[2] = acc[2] * inv + bA.z; h[3] = acc[3] * inv + bA.w;
    h[4] = acc[4] * inv + bB.x; h[5] = acc[5] * inv + bB.y;
    h[6] = acc[6] * inv + bB.z; h[7] = acc[7] * inv + bB.w;

    float s = 0.f;
    #pragma unroll
    for (int d = 0; d < 8; ++d) s += h[d];
    #pragma unroll
    for (int off = 8; off > 0; off >>= 1) s += __shfl_xor(s, off, 64);
    float mu = s * (1.0f / 128.0f);

    float dv[8], vv = 0.f;
    #pragma unroll
    for (int d = 0; d < 8; ++d) { dv[d] = h[d] - mu; vv += dv[d] * dv[d]; }
    #pragma unroll
    for (int off = 8; off > 0; off >>= 1) vv += __shfl_xor(vv, off, 64);
    float rs = rsqrtf(vv * (1.0f / 128.0f) + 1e-5f);

    float4 gA = ((const float4*)ln_g)[2 * g];
    float4 gB = ((const float4*)ln_g)[2 * g + 1];
    float4 eA = ((const float4*)ln_b)[2 * g];
    float4 eB = ((const float4*)ln_b)[2 * g + 1];
    float gg[8] = {gA.x, gA.y, gA.z, gA.w, gB.x, gB.y, gB.z, gB.w};
    float ee[8] = {eA.x, eA.y, eA.z, eA.w, eB.x, eB.y, eB.z, eB.w};
    union { __bf16 b[8]; uint4 u; } pk;
    #pragma unroll
    for (int d = 0; d < 8; ++d) {
        float r = dv[d] * rs * gg[d] + ee[d];
        pk.b[d] = (__bf16)(r > 0.f ? r : 0.f);
    }
    lds_r[el * 16 + g] = pk.u;
    __syncthreads();

    if (wave == 0) {   // out tile: [16 edges x 128] @ [128 x 32pad]
        const int m = lane & 15, q = lane >> 4;
        const __bf16* lr = (const __bf16*)lds_r;
        const bf16x8* fw = (const bf16x8*)w2f;
        f32x4 a0 = (f32x4){0.f, 0.f, 0.f, 0.f};
        f32x4 a1 = (f32x4){0.f, 0.f, 0.f, 0.f};
        #pragma unroll
        for (int ks = 0; ks < 4; ++ks) {
            bf16x8 a = *(const bf16x8*)(lr + m * 128 + ks * 32 + q * 8);
            a0 = __builtin_amdgcn_mfma_f32_16x16x32_bf16(a, fw[(ks * 2 + 0) * 64 + lane], a0, 0, 0, 0);
            a1 = __builtin_amdgcn_mfma_f32_16x16x32_bf16(a, fw[(ks * 2 + 1) * 64 + lane], a1, 0, 0, 0);
        }
        int rowb = blockIdx.x * 16 + q * 4;
        float bm = b2[m];
        float b16 = b2[16];
        #pragma unroll
        for (int r = 0; r < 4; ++r) {
            out[(size_t)(rowb + r) * EDGE_DIM + m] = a0[r] + bm;
            if (m == 0) out[(size_t)(rowb + r) * EDGE_DIM + 16] = a1[r] + b16;
        }
    }
}

extern "C" void kernel_launch(void* const* d_in, const int* in_sizes, int n_in,
                              void* d_out, int out_size, void* d_ws, size_t ws_size,
                              hipStream_t stream) {
    const float* nf  = (const float*)d_in[0];
    const int*   idx = (const int*)d_in[1];
    const float* W1  = (const float*)d_in[2];
    const float* b1  = (const float*)d_in[3];
    const float* g   = (const float*)d_in[4];
    const float* be  = (const float*)d_in[5];
    const float* W2  = (const float*)d_in[6];
    const float* b2  = (const float*)d_in[7];
    float* out = (float*)d_out;

    char* ws = (char*)d_ws;
    __bf16* P       = (__bf16*)ws;
    int*    counts2 = (int*)(ws + 25600000);
    int*    slots   = (int*)(ws + 28800000);
    __bf16* W1F     = (__bf16*)(ws + 41600000);
    __bf16* W2F     = (__bf16*)(ws + 41665536);

    int stride = (in_sizes[1] == 2 * NUM_CONN) ? 1 : 2;

    prep_kernel<<<196, 256, 0, stream>>>(W1, W2, W1F, W2F, counts2);
    front_kernel<<<FRONT_BLOCKS, 256, 0, stream>>>(idx, stride, counts2, slots, nf, W1F, P);
    edge_kernel<<<NUM_EDGES / 16, 256, 0, stream>>>((const uint4*)P, counts2, slots,
                                                    b1, g, be, W2F, b2, out);
}